// Round 1
// baseline (2012.576 us; speedup 1.0000x reference)
//
#include <hip/hip_runtime.h>

#define B_SZ   256
#define T_SZ   1000
#define N_IN   128
#define UNITS  512

// ---------------------------------------------------------------------------
// Phase 1: C[M,512] = X[M,128] @ W[128,512],  M = B*T = 256000, fp32.
// 128x128 output tile per WG, 256 threads, 8x8 micro-tile (n split 4+4 @ +64).
// Accumulation is strictly ascending-k with a single accumulator per output
// (fmaf chain) to track BLAS-style inner-kernel ordering.
// ---------------------------------------------------------------------------
__global__ __launch_bounds__(256) void gemm_in(const float* __restrict__ X,
                                               const float* __restrict__ W,
                                               float* __restrict__ C) {
    __shared__ __align__(16) float As[32][128];  // As[k][m] (transposed x tile)
    __shared__ __align__(16) float Bs[32][128];  // Bs[k][n]

    const int tid = threadIdx.x;
    const int ntile = blockIdx.x & 3;        // 512/128 = 4 n-tiles
    const int mtile = blockIdx.x >> 2;       // 2000 m-tiles
    const int m0 = mtile * 128, n0 = ntile * 128;
    const int tm  = (tid >> 4) * 8;          // 16 m-groups of 8
    const int tn4 = (tid & 15) * 4;          // 16 n-groups of 4 (+ mirror at +64)

    float acc[8][8];
#pragma unroll
    for (int i = 0; i < 8; ++i)
#pragma unroll
        for (int j = 0; j < 8; ++j) acc[i][j] = 0.0f;

    for (int k0 = 0; k0 < 128; k0 += 32) {
        __syncthreads();
        // stage A tile: x[m0..m0+127][k0..k0+31] -> As[k][m] (transpose on store)
#pragma unroll
        for (int r = 0; r < 4; ++r) {
            int li  = r * 256 + tid;          // 0..1023 float4 slots
            int row = li >> 3;                // 0..127
            int ch  = li & 7;                 // 0..7 (4 floats each)
            float4 a = *(const float4*)&X[(size_t)(m0 + row) * 128 + k0 + ch * 4];
            As[ch * 4 + 0][row] = a.x;
            As[ch * 4 + 1][row] = a.y;
            As[ch * 4 + 2][row] = a.z;
            As[ch * 4 + 3][row] = a.w;
        }
        // stage B tile: W[k0..k0+31][n0..n0+127] -> Bs[k][n] (direct)
#pragma unroll
        for (int r = 0; r < 4; ++r) {
            int li = r * 256 + tid;
            int kk = li >> 5;                 // 0..31
            int n4 = li & 31;                 // 0..31
            *(float4*)&Bs[kk][n4 * 4] =
                *(const float4*)&W[(size_t)(k0 + kk) * 512 + n0 + n4 * 4];
        }
        __syncthreads();

#pragma unroll 8
        for (int k = 0; k < 32; ++k) {
            float4 a0 = *(const float4*)&As[k][tm];
            float4 a1 = *(const float4*)&As[k][tm + 4];
            float4 b0 = *(const float4*)&Bs[k][tn4];
            float4 b1 = *(const float4*)&Bs[k][tn4 + 64];
            const float av[8] = {a0.x, a0.y, a0.z, a0.w, a1.x, a1.y, a1.z, a1.w};
            const float bv[8] = {b0.x, b0.y, b0.z, b0.w, b1.x, b1.y, b1.z, b1.w};
#pragma unroll
            for (int i = 0; i < 8; ++i)
#pragma unroll
                for (int j = 0; j < 8; ++j)
                    acc[i][j] = fmaf(av[i], bv[j], acc[i][j]);
        }
    }

#pragma unroll
    for (int i = 0; i < 8; ++i) {
        size_t row = (size_t)(m0 + tm + i) * 512;
        float4 c0 = make_float4(acc[i][0], acc[i][1], acc[i][2], acc[i][3]);
        float4 c1 = make_float4(acc[i][4], acc[i][5], acc[i][6], acc[i][7]);
        *(float4*)&C[row + n0 + tn4]      = c0;
        *(float4*)&C[row + n0 + 64 + tn4] = c1;
    }
}

// ---------------------------------------------------------------------------
// Phase 2: ALIF scan. One workgroup per batch row (256 WGs x 512 threads).
// Thread u owns unit u. i_in was staged into IO ([B,T,U]) by gemm_in; each
// step reads it and overwrites the same slot with the spike output (same
// thread: read-before-write, deterministic).
// z @ W_rec exploits binary z: sum rows of W_rec for active j, in strictly
// ascending j order (deterministic; matches a sequential dense dot since the
// zero terms are exact fp no-ops). Diagonal is masked (ref zeroes it).
// Elementwise math uses __f*_rn intrinsics in the reference's exact op order.
// ---------------------------------------------------------------------------
__global__ __launch_bounds__(512) void alif_scan(const float* __restrict__ Wr,
                                                 float* __restrict__ IO) {
    const int b = blockIdx.x;
    const int u = threadIdx.x;
    const int w = u >> 6;                    // wave id (0..7)
    const int lane = u & 63;

    __shared__ __align__(16) int s_list[520];
    __shared__ int s_cnt[8];
    __shared__ int s_total;

    // constants: correctly-rounded fp32 of the double values; "1 - c" folded
    // at compile time in fp32 (matches numpy's fp32 subtraction).
    const float DECAY   = 0.95122942450071400910f;   // exp(-1/20)
    const float OMD     = 1.0f - DECAY;
    const float DECAY_B = 0.99501247919268232342f;   // exp(-1/200)
    const float OMDB    = 1.0f - DECAY_B;

    float v = 0.0f, ad = 0.0f, z = 0.0f;

    const float* wcol = Wr + u;                       // column u of W_rec
    float* io = IO + (size_t)b * (T_SZ * UNITS) + u;  // [t][u] slab for batch b

    if (u == 0) s_total = 0;
    __syncthreads();

    for (int t = 0; t < T_SZ; ++t) {
        float i_in_v = io[t * UNITS];
        int cnt = s_total;

        // i_rec = sum over active j (ascending) of W_rec[j][u], diag masked
        float acc = 0.0f;
        int k = 0;
        int kfull = cnt & ~7;
        for (; k < kfull; k += 8) {
            int4 ja = *(const int4*)(s_list + k);
            int4 jb = *(const int4*)(s_list + k + 4);
            float w0 = wcol[(size_t)ja.x * UNITS];
            float w1 = wcol[(size_t)ja.y * UNITS];
            float w2 = wcol[(size_t)ja.z * UNITS];
            float w3 = wcol[(size_t)ja.w * UNITS];
            float w4 = wcol[(size_t)jb.x * UNITS];
            float w5 = wcol[(size_t)jb.y * UNITS];
            float w6 = wcol[(size_t)jb.z * UNITS];
            float w7 = wcol[(size_t)jb.w * UNITS];
            acc = __fadd_rn(acc, (ja.x != u) ? w0 : 0.0f);
            acc = __fadd_rn(acc, (ja.y != u) ? w1 : 0.0f);
            acc = __fadd_rn(acc, (ja.z != u) ? w2 : 0.0f);
            acc = __fadd_rn(acc, (ja.w != u) ? w3 : 0.0f);
            acc = __fadd_rn(acc, (jb.x != u) ? w4 : 0.0f);
            acc = __fadd_rn(acc, (jb.y != u) ? w5 : 0.0f);
            acc = __fadd_rn(acc, (jb.z != u) ? w6 : 0.0f);
            acc = __fadd_rn(acc, (jb.w != u) ? w7 : 0.0f);
        }
        if (k < cnt) {  // tail; list is padded with index 0 past cnt
            int4 ja = *(const int4*)(s_list + k);
            int4 jb = *(const int4*)(s_list + k + 4);
            float w0 = wcol[(size_t)ja.x * UNITS];
            float w1 = wcol[(size_t)ja.y * UNITS];
            float w2 = wcol[(size_t)ja.z * UNITS];
            float w3 = wcol[(size_t)ja.w * UNITS];
            float w4 = wcol[(size_t)jb.x * UNITS];
            float w5 = wcol[(size_t)jb.y * UNITS];
            float w6 = wcol[(size_t)jb.z * UNITS];
            float w7 = wcol[(size_t)jb.w * UNITS];
            acc = __fadd_rn(acc, (k + 0 < cnt && ja.x != u) ? w0 : 0.0f);
            acc = __fadd_rn(acc, (k + 1 < cnt && ja.y != u) ? w1 : 0.0f);
            acc = __fadd_rn(acc, (k + 2 < cnt && ja.z != u) ? w2 : 0.0f);
            acc = __fadd_rn(acc, (k + 3 < cnt && ja.w != u) ? w3 : 0.0f);
            acc = __fadd_rn(acc, (k + 4 < cnt && jb.x != u) ? w4 : 0.0f);
            acc = __fadd_rn(acc, (k + 5 < cnt && jb.y != u) ? w5 : 0.0f);
            acc = __fadd_rn(acc, (k + 6 < cnt && jb.z != u) ? w6 : 0.0f);
            acc = __fadd_rn(acc, (k + 7 < cnt && jb.w != u) ? w7 : 0.0f);
        }

        // elementwise state update — exact reference op order, no contraction
        float newb = __fadd_rn(__fmul_rn(DECAY_B, ad), __fmul_rn(OMDB, z));
        float thr  = __fadd_rn(0.01f, __fmul_rn(newb, 1.6f));
        float it   = __fadd_rn(__fadd_rn(i_in_v, acc), 0.0f);      // + ADD_CUR
        float ires = __fmul_rn(__fmul_rn(z, thr), 1.0f);           // * DT
        float newv = __fsub_rn(
            __fadd_rn(__fmul_rn(DECAY, v), __fmul_rn(OMD, it)), ires);
        // spike((newv-thr)/thr) > 0  <=>  newv > thr  (thr > 0 always)
        float zn = (newv > thr) ? 1.0f : 0.0f;      // refractory is a no-op

        io[t * UNITS] = zn;                          // overwrite i_in with z
        v = newv; ad = newb; z = zn;

        // rebuild active list for next step (deterministic ascending order)
        unsigned long long m = __ballot(zn > 0.0f);
        if (lane == 0) s_cnt[w] = __popcll(m);
        __syncthreads();   // [A] everyone done reading old list; cnts visible

        int base = 0, total = 0;
#pragma unroll
        for (int i = 0; i < 8; ++i) {
            int c = s_cnt[i];
            total += c;
            if (i < w) base += c;
        }
        if (zn > 0.0f) {
            int pos = base + __popcll(m & ((1ull << lane) - 1ull));
            s_list[pos] = u;
        }
        if (u == 0) s_total = total;
        if (u < 8) s_list[total + u] = 0;            // pad for int4 tail reads
        __syncthreads();   // [C] list ready
    }
}

extern "C" void kernel_launch(void* const* d_in, const int* in_sizes, int n_in,
                              void* d_out, int out_size, void* d_ws, size_t ws_size,
                              hipStream_t stream) {
    (void)in_sizes; (void)n_in; (void)out_size; (void)d_ws; (void)ws_size;
    const float* x     = (const float*)d_in[0];   // [B,T,128]
    const float* W_in  = (const float*)d_in[1];   // [128,512]
    const float* W_rec = (const float*)d_in[2];   // [512,512]
    float* out = (float*)d_out;                   // [B,T,512]

    // Phase 1: i_in staged directly into d_out (layout matches [B,T,U]).
    gemm_in<<<dim3((B_SZ * T_SZ / 128) * (UNITS / 128)), dim3(256), 0, stream>>>(
        x, W_in, out);
    // Phase 2: sequential scan, one WG per batch row; overwrites i_in with z.
    alif_scan<<<dim3(B_SZ), dim3(512), 0, stream>>>(W_rec, out);
}